// Round 14
// baseline (2121.478 us; speedup 1.0000x reference)
//
#include <hip/hip_runtime.h>
#include <hip/hip_bf16.h>

#define TT 512
#define NWGS 128       // 128 WGs x 4 batch rows
#define NTHREADS 256   // 4 waves, 1 wave/SIMD
#define CH 32          // steps per chunk
#define NCH 16         // 512/32
#define SLOT 576       // shorts per h slot: 4 rows x 144 (288B row stride)
#define RSTR 144

typedef float f32x4 __attribute__((ext_vector_type(4)));
typedef unsigned int uint4v __attribute__((ext_vector_type(4)));

// Raw barrier: LDS drain only; global loads stay in flight.
#define BAR() asm volatile("s_waitcnt lgkmcnt(0)\n\ts_barrier" ::: "memory")

__device__ __forceinline__ unsigned short f2bf(float f) {
  unsigned int u = __float_as_uint(f);
  u = u + 0x7FFFu + ((u >> 16) & 1u);
  return (unsigned short)(u >> 16);
}
__device__ __forceinline__ float sigm(float x) {
  return __builtin_amdgcn_rcpf(1.f + __builtin_amdgcn_exp2f(-1.44269504f * x));
}
__device__ __forceinline__ float tanh_(float x) {
  return 1.f - 2.f * __builtin_amdgcn_rcpf(1.f + __builtin_amdgcn_exp2f(2.88539008f * x));
}
__device__ __forceinline__ float softplus_(float x) {
  if (x > 15.f) return x;
  float e = __builtin_amdgcn_exp2f(1.44269504f * x);
  return 0.69314718f * __builtin_amdgcn_logf(1.f + e);
}

// Load a 16B weight fragment and pin it into an AGPR quad.
__device__ __forceinline__ uint4v pin_a(const unsigned short* p) {
  uint4v u = *(const uint4v*)p;
  asm volatile("" : "+a"(u));
  return u;
}

// MFMA, A from VGPR (activations), B from AGPR (resident weights).
__device__ __forceinline__ void mfma_va(f32x4& acc, uint4v a, uint4v b) {
  asm volatile("v_mfma_f32_16x16x32_bf16 %0, %1, %2, %0" : "+v"(acc) : "v"(a), "a"(b));
}
// FINAL write of an accumulator before VALU/shuffle reads: hazard nops FUSED
// into the same asm block (no scheduler insertion point — rule-18 discipline).
__device__ __forceinline__ void mfma_va_end(f32x4& acc, uint4v a, uint4v b) {
  asm volatile("v_mfma_f32_16x16x32_bf16 %0, %1, %2, %0\n\ts_nop 7"
               : "+v"(acc) : "v"(a), "a"(b));
}

// Pack a [512][K] f32 weight matrix into bf16 B-fragment order:
// dst[((tau*ktiles + c)*64 + l)*8 + i] = W[tau*16 + (l&15)][c*32 + 8*(l>>4) + i]
__global__ void pack_w_kern(const float* __restrict__ src, unsigned short* __restrict__ dst,
                            int K, int ktiles) {
  int tid = blockIdx.x * 256 + threadIdx.x;
  int total = 32 * ktiles * 64;
  if (tid >= total) return;
  int l = tid & 63;
  int c = (tid >> 6) % ktiles;
  int tau = tid / (64 * ktiles);
  int n = tau * 16 + (l & 15);
  int k0 = c * 32 + 8 * (l >> 4);
  unsigned short o[8];
#pragma unroll
  for (int i = 0; i < 8; ++i) {
    int k = k0 + i;
    float v = (k < K) ? src[n * K + k] : 0.f;
    o[i] = f2bf(v);
  }
  *(uint4v*)(dst + (size_t)tid * 8) = *(const uint4v*)o;
}

// Build x0 (concat cont feats + embeddings), bf16, A-fragment order over 32
// 16-row batch tiles, K padded 22->32.
__global__ void pack_x0_kern(const float* __restrict__ xc, const int* __restrict__ idxs,
                             const int* __restrict__ idxi, const float* __restrict__ es,
                             const float* __restrict__ ei, unsigned short* __restrict__ dst) {
  int tid = blockIdx.x * 256 + threadIdx.x;
  if (tid >= TT * 32 * 64) return;
  int l = tid & 63;
  int b = (tid >> 6) & 31;
  int t = tid >> 11;
  int bi = b * 16 + (l & 15);
  int k0 = 8 * (l >> 4);
  int si = idxs[bi * TT + t];
  int it = idxi[bi * TT + t];
  const float* xr = xc + ((size_t)bi * TT + t) * 12;
  unsigned short o[8];
#pragma unroll
  for (int i = 0; i < 8; ++i) {
    int k = k0 + i;
    float v;
    if (k < 12)      v = xr[k];
    else if (k < 17) v = es[si * 5 + (k - 12)];
    else if (k < 22) v = ei[it * 5 + (k - 17)];
    else             v = 0.f;
    o[i] = f2bf(v);
  }
  *(uint4v*)(dst + (size_t)tid * 8) = *(const uint4v*)o;
}

// Gaussian head for one step; reads compact h2 slot [4][RSTR]. Wave 0 only.
__device__ __forceinline__ void head_step(
    int b, int t, const unsigned short* slotbase,
    const float* wmS, const float* waS, const float* vS,
    float bmv, float bav, float* out) {
  const int tid = threadIdx.x;
  if (tid >= 64) return;
  int s_ = tid & 7, hd = (tid >> 3) & 1, bi = tid >> 4;  // bi 0..3
  const float* wv = hd ? waS : wmS;
  const uint4v* hp = (const uint4v*)(slotbase + bi * RSTR + s_ * 16);
  uint4v q0 = hp[0], q1 = hp[1];
  const f32x4* wp4 = (const f32x4*)(wv + s_ * 16);
  f32x4 w0 = wp4[0], w1 = wp4[1], w2 = wp4[2], w3 = wp4[3];
  float part = 0.f;
  part += __uint_as_float(q0[0] << 16) * w0[0];
  part += __uint_as_float(q0[0] & 0xffff0000u) * w0[1];
  part += __uint_as_float(q0[1] << 16) * w0[2];
  part += __uint_as_float(q0[1] & 0xffff0000u) * w0[3];
  part += __uint_as_float(q0[2] << 16) * w1[0];
  part += __uint_as_float(q0[2] & 0xffff0000u) * w1[1];
  part += __uint_as_float(q0[3] << 16) * w1[2];
  part += __uint_as_float(q0[3] & 0xffff0000u) * w1[3];
  part += __uint_as_float(q1[0] << 16) * w2[0];
  part += __uint_as_float(q1[0] & 0xffff0000u) * w2[1];
  part += __uint_as_float(q1[1] << 16) * w2[2];
  part += __uint_as_float(q1[1] & 0xffff0000u) * w2[3];
  part += __uint_as_float(q1[2] << 16) * w3[0];
  part += __uint_as_float(q1[2] & 0xffff0000u) * w3[1];
  part += __uint_as_float(q1[3] << 16) * w3[2];
  part += __uint_as_float(q1[3] & 0xffff0000u) * w3[3];
  part += __shfl_xor(part, 1);
  part += __shfl_xor(part, 2);
  part += __shfl_xor(part, 4);
  if (s_ == 0) {
    float val = part + (hd ? bav : bmv);
    if (hd) val = softplus_(val);
    out[(((size_t)(b * 4 + bi)) * TT + t) * 2 + hd] = val * vS[bi];
  }
}

// One layer's scan over one chunk. 4 waves, 1/SIMD: wave w owns gate-tiles
// tau = g*8 + w*2 + s (g=gate, s=subtile). Weights AGPR-resident (256/wave).
// Ping-pong chunk buffers; shuffle-compact epilogue per subtile.
template<int L>
__device__ __forceinline__ void scan_chunk(
    int k, int b, const unsigned short* wp_ih, const unsigned short* wp_hh,
    const unsigned short* x0p, const unsigned short* inb, unsigned short* outb,
    unsigned short* carry, float (&cc)[2], const float (&bia)[2][4],
    const float* wmS, const float* waS, const float* vS,
    float bmv, float bav, float* out) {
  const int tid = threadIdx.x;
  const int l = tid & 63;
  const int w = tid >> 6;  // wave 0..3
  const int afrag = (l & 3) * RSTR + 8 * (l >> 4);  // + c*32 per k-tile (dup rows)
  const int xlane = (l & 48) | ((b & 3) * 4 + (l & 3));
  const int r_ = l >> 4;
  const int src = l & 15;

  // -------- weight burst into AGPRs (groups of 16, sched_barrier caps spike) --
  uint4v ihf[2][4][4], hhf[2][4][4];
  if (L == 0) {
#pragma unroll
    for (int s = 0; s < 2; ++s)
#pragma unroll
      for (int g = 0; g < 4; ++g)
        ihf[s][g][0] = pin_a(wp_ih + ((size_t)(g * 8 + w * 2 + s) * 64 + l) * 8);
    __builtin_amdgcn_sched_barrier(0);
  } else {
#pragma unroll
    for (int s = 0; s < 2; ++s) {
#pragma unroll
      for (int g = 0; g < 4; ++g)
#pragma unroll
        for (int c = 0; c < 4; ++c)
          ihf[s][g][c] =
              pin_a(wp_ih + ((size_t)((g * 8 + w * 2 + s) * 4 + c) * 64 + l) * 8);
      __builtin_amdgcn_sched_barrier(0);
    }
  }
#pragma unroll
  for (int s = 0; s < 2; ++s) {
#pragma unroll
    for (int g = 0; g < 4; ++g)
#pragma unroll
      for (int c = 0; c < 4; ++c)
        hhf[s][g][c] =
            pin_a(wp_hh + ((size_t)((g * 8 + w * 2 + s) * 4 + c) * 64 + l) * 8);
    __builtin_amdgcn_sched_barrier(0);
  }
  asm volatile("s_nop 1");  // accvgpr_write -> MFMA B-read wait states

  uint4v xcur;
  if (L == 0)
    xcur = *(const uint4v*)(x0p + (((size_t)(k * CH) * 32 + (b >> 2)) * 64 + xlane) * 8);

  for (int tt = 0; tt < CH; ++tt) {
    const int t = k * CH + tt;
    BAR();  // step tt-1 writes visible
    if (L == 2 && tt > 0)
      head_step(b, t - 1, outb + (tt - 1) * SLOT, wmS, waS, vS, bmv, bav, out);
    uint4v xnxt, inF[4], ah[4];
    if (L == 0) {
      int tn = (tt < CH - 1) ? t + 1 : t;
      xnxt = *(const uint4v*)(x0p + (((size_t)tn * 32 + (b >> 2)) * 64 + xlane) * 8);
    } else {
#pragma unroll
      for (int c = 0; c < 4; ++c)
        inF[c] = *(const uint4v*)(inb + tt * SLOT + afrag + c * 32);
    }
    const unsigned short* ahb = (tt == 0) ? carry : outb + (tt - 1) * SLOT;
#pragma unroll
    for (int c = 0; c < 4; ++c) ah[c] = *(const uint4v*)(ahb + afrag + c * 32);
    f32x4 acc[2][4];
#pragma unroll
    for (int s = 0; s < 2; ++s)
#pragma unroll
      for (int g = 0; g < 4; ++g) {
        float bb = bia[s][g];
        f32x4 z = {bb, bb, bb, bb};
        acc[s][g] = z;
      }
    if (L == 0) {
#pragma unroll
      for (int s = 0; s < 2; ++s)
#pragma unroll
        for (int g = 0; g < 4; ++g) mfma_va(acc[s][g], xcur, ihf[s][g][0]);
    } else {
#pragma unroll
      for (int c = 0; c < 4; ++c)
#pragma unroll
        for (int s = 0; s < 2; ++s)
#pragma unroll
          for (int g = 0; g < 4; ++g) mfma_va(acc[s][g], inF[c], ihf[s][g][c]);
    }
#pragma unroll
    for (int c = 0; c < 4; ++c)
#pragma unroll
      for (int s = 0; s < 2; ++s)
#pragma unroll
        for (int g = 0; g < 4; ++g) {
          if (c == 3) mfma_va_end(acc[s][g], ah[c], hhf[s][g][c]);  // fused s_nop 7
          else        mfma_va(acc[s][g], ah[c], hhf[s][g][c]);
        }

    // -------- per-subtile shuffle-compact epilogue (1 cell/lane/subtile) ------
#pragma unroll
    for (int s = 0; s < 2; ++s) {
      float gv[4];
#pragma unroll
      for (int g = 0; g < 4; ++g) {
        float v0 = __shfl(acc[s][g][0], src);
        float v1 = __shfl(acc[s][g][1], src);
        float v2 = __shfl(acc[s][g][2], src);
        float v3 = __shfl(acc[s][g][3], src);
        float va = (r_ & 1) ? v1 : v0;
        float vb = (r_ & 1) ? v3 : v2;
        gv[g] = (r_ & 2) ? vb : va;
      }
      float ig = sigm(gv[0]);
      float fg = sigm(gv[1]);
      float gt = tanh_(gv[2]);
      float og = sigm(gv[3]);
      cc[s] = fg * cc[s] + ig * gt;
      float h = og * tanh_(cc[s]);
      unsigned short hb = f2bf(h);
      int js = (w * 2 + s) * 16 + src;
      outb[tt * SLOT + r_ * RSTR + js] = hb;
      if (tt == CH - 1) carry[r_ * RSTR + js] = hb;
    }
    if (L == 0) xcur = xnxt;
  }
  if (L == 2) {
    BAR();
    head_step(b, k * CH + CH - 1, outb + (CH - 1) * SLOT, wmS, waS, vS, bmv, bav, out);
  }
}

__attribute__((amdgpu_waves_per_eu(1, 1)))  // 1 wave/SIMD -> 512-reg budget
__global__ void __launch_bounds__(NTHREADS)
lstm_seq4_kern(
    const unsigned short* __restrict__ wp_ih0, const unsigned short* __restrict__ wp_hh0,
    const unsigned short* __restrict__ wp_ih1, const unsigned short* __restrict__ wp_hh1,
    const unsigned short* __restrict__ wp_ih2, const unsigned short* __restrict__ wp_hh2,
    const unsigned short* __restrict__ x0p,
    const float* __restrict__ b0, const float* __restrict__ b1, const float* __restrict__ b2,
    const float* __restrict__ Wm, const float* __restrict__ bm,
    const float* __restrict__ Wa, const float* __restrict__ ba,
    const float* __restrict__ v, float* __restrict__ out) {
  __shared__ __align__(16) unsigned short bufS[2][CH * SLOT];  // ping-pong (72 KB)
  __shared__ __align__(16) unsigned short carryS[3 * SLOT];    // per-layer h carry
  __shared__ __align__(16) float wmS[128], waS[128];
  __shared__ float vS[4];

  const int tid = threadIdx.x;
  const int b = blockIdx.x;      // 0..127, batch rows [b*4, b*4+4)
  const int l = tid & 63;
  const int w = tid >> 6;        // wave 0..3

  for (int i = tid; i < 3 * SLOT; i += NTHREADS) carryS[i] = 0;
  if (tid < 128) { wmS[tid] = Wm[tid]; waS[tid] = Wa[tid]; }
  if (tid < 4) vS[tid] = v[b * 4 + tid];

  float bia0[2][4], bia1[2][4], bia2[2][4];
#pragma unroll
  for (int s = 0; s < 2; ++s)
#pragma unroll
    for (int g = 0; g < 4; ++g) {
      int js = (w * 2 + s) * 16 + (l & 15);
      bia0[s][g] = b0[g * 128 + js];
      bia1[s][g] = b1[g * 128 + js];
      bia2[s][g] = b2[g * 128 + js];
    }
  float cc0[2] = {0.f, 0.f}, cc1[2] = {0.f, 0.f}, cc2[2] = {0.f, 0.f};
  const float bmv = bm[0], bav = ba[0];

  // Laundered weight base pointers: block LICM of bursts out of the chunk loop.
  size_t p_ih0 = (size_t)wp_ih0, p_hh0 = (size_t)wp_hh0;
  size_t p_ih1 = (size_t)wp_ih1, p_hh1 = (size_t)wp_hh1;
  size_t p_ih2 = (size_t)wp_ih2, p_hh2 = (size_t)wp_hh2;

  __syncthreads();

  for (int k = 0; k < NCH; ++k) {
    asm volatile("" : "+s"(p_ih0), "+s"(p_hh0), "+s"(p_ih1), "+s"(p_hh1),
                      "+s"(p_ih2), "+s"(p_hh2));
    scan_chunk<0>(k, b, (const unsigned short*)p_ih0, (const unsigned short*)p_hh0,
                  x0p, nullptr, bufS[0], carryS, cc0, bia0, wmS, waS, vS, bmv, bav, out);
    scan_chunk<1>(k, b, (const unsigned short*)p_ih1, (const unsigned short*)p_hh1,
                  x0p, bufS[0], bufS[1], carryS + SLOT, cc1, bia1,
                  wmS, waS, vS, bmv, bav, out);
    scan_chunk<2>(k, b, (const unsigned short*)p_ih2, (const unsigned short*)p_hh2,
                  x0p, bufS[1], bufS[0], carryS + 2 * SLOT, cc2, bia2,
                  wmS, waS, vS, bmv, bav, out);
  }
}

extern "C" void kernel_launch(void* const* d_in, const int* in_sizes, int n_in,
                              void* d_out, int out_size, void* d_ws, size_t ws_size,
                              hipStream_t stream) {
  const float* x_cont    = (const float*)d_in[0];
  const int*   idx_shops = (const int*)d_in[1];
  const int*   idx_items = (const int*)d_in[2];
  const float* v         = (const float*)d_in[3];
  const float* emb_shops = (const float*)d_in[4];
  const float* emb_items = (const float*)d_in[5];
  const float* Wih0 = (const float*)d_in[6];
  const float* Whh0 = (const float*)d_in[7];
  const float* b0   = (const float*)d_in[8];
  const float* Wih1 = (const float*)d_in[9];
  const float* Whh1 = (const float*)d_in[10];
  const float* b1   = (const float*)d_in[11];
  const float* Wih2 = (const float*)d_in[12];
  const float* Whh2 = (const float*)d_in[13];
  const float* b2   = (const float*)d_in[14];
  const float* Wm   = (const float*)d_in[15];
  const float* bm   = (const float*)d_in[16];
  const float* Wa   = (const float*)d_in[17];
  const float* ba   = (const float*)d_in[18];
  float* out = (float*)d_out;

  unsigned short* ws = (unsigned short*)d_ws;
  unsigned short* wp_ih0 = ws;                  // 32*1*64*8   = 16384 el
  unsigned short* wp_hh0 = wp_ih0 + 16384;      // 32*4*64*8   = 65536 el
  unsigned short* wp_ih1 = wp_hh0 + 65536;
  unsigned short* wp_hh1 = wp_ih1 + 65536;
  unsigned short* wp_ih2 = wp_hh1 + 65536;
  unsigned short* wp_hh2 = wp_ih2 + 65536;
  unsigned short* x0p    = wp_hh2 + 65536;      // 512*32*64*8 = 8388608 el (17.5 MB total)

  pack_w_kern<<<8, 256, 0, stream>>>(Wih0, wp_ih0, 22, 1);
  pack_w_kern<<<32, 256, 0, stream>>>(Whh0, wp_hh0, 128, 4);
  pack_w_kern<<<32, 256, 0, stream>>>(Wih1, wp_ih1, 128, 4);
  pack_w_kern<<<32, 256, 0, stream>>>(Whh1, wp_hh1, 128, 4);
  pack_w_kern<<<32, 256, 0, stream>>>(Wih2, wp_ih2, 128, 4);
  pack_w_kern<<<32, 256, 0, stream>>>(Whh2, wp_hh2, 128, 4);
  pack_x0_kern<<<4096, 256, 0, stream>>>(x_cont, idx_shops, idx_items,
                                         emb_shops, emb_items, x0p);
  lstm_seq4_kern<<<NWGS, NTHREADS, 0, stream>>>(wp_ih0, wp_hh0, wp_ih1, wp_hh1,
                                                wp_ih2, wp_hh2, x0p,
                                                b0, b1, b2, Wm, bm, Wa, ba, v, out);
}

// Round 15
// 1373.841 us; speedup vs baseline: 1.5442x; 1.5442x over previous
//
#include <hip/hip_runtime.h>
#include <hip/hip_bf16.h>

#define TT 512
#define NWGS 128       // 128 WGs x 4 batch rows
#define NTHREADS 512   // 8 waves, 2/SIMD
#define CH 32          // steps per chunk
#define NCH 16         // 512/32
#define SLOT 576       // shorts per h slot: 4 rows x 144 (288B row stride)
#define RSTR 144

typedef float f32x4 __attribute__((ext_vector_type(4)));
typedef unsigned int uint4v __attribute__((ext_vector_type(4)));

// Raw barrier: LDS drain only; global loads stay in flight.
#define BAR() asm volatile("s_waitcnt lgkmcnt(0)\n\ts_barrier" ::: "memory")

__device__ __forceinline__ unsigned short f2bf(float f) {
  unsigned int u = __float_as_uint(f);
  u = u + 0x7FFFu + ((u >> 16) & 1u);
  return (unsigned short)(u >> 16);
}
__device__ __forceinline__ float sigm(float x) {
  return __builtin_amdgcn_rcpf(1.f + __builtin_amdgcn_exp2f(-1.44269504f * x));
}
__device__ __forceinline__ float tanh_(float x) {
  return 1.f - 2.f * __builtin_amdgcn_rcpf(1.f + __builtin_amdgcn_exp2f(2.88539008f * x));
}
__device__ __forceinline__ float softplus_(float x) {
  if (x > 15.f) return x;
  float e = __builtin_amdgcn_exp2f(1.44269504f * x);
  return 0.69314718f * __builtin_amdgcn_logf(1.f + e);
}

// Load a 16B weight fragment and pin it into an AGPR quad.
__device__ __forceinline__ uint4v pin_a(const unsigned short* p) {
  uint4v u = *(const uint4v*)p;
  asm volatile("" : "+a"(u));
  return u;
}

// MFMA, A from VGPR (activations), B from AGPR (resident weights).
__device__ __forceinline__ void mfma_va(f32x4& acc, uint4v a, uint4v b) {
  asm volatile("v_mfma_f32_16x16x32_bf16 %0, %1, %2, %0" : "+v"(acc) : "v"(a), "a"(b));
}
// FINAL write of an accumulator before VALU reads: hazard nops FUSED into the
// same asm block (rule-18 discipline; detached nops re-open the window: R13).
__device__ __forceinline__ void mfma_va_end(f32x4& acc, uint4v a, uint4v b) {
  asm volatile("v_mfma_f32_16x16x32_bf16 %0, %1, %2, %0\n\ts_nop 7"
               : "+v"(acc) : "v"(a), "a"(b));
}

// Pack a [512][K] f32 weight matrix into bf16 B-fragment order:
// dst[((tau*ktiles + c)*64 + l)*8 + i] = W[tau*16 + (l&15)][c*32 + 8*(l>>4) + i]
__global__ void pack_w_kern(const float* __restrict__ src, unsigned short* __restrict__ dst,
                            int K, int ktiles) {
  int tid = blockIdx.x * 256 + threadIdx.x;
  int total = 32 * ktiles * 64;
  if (tid >= total) return;
  int l = tid & 63;
  int c = (tid >> 6) % ktiles;
  int tau = tid / (64 * ktiles);
  int n = tau * 16 + (l & 15);
  int k0 = c * 32 + 8 * (l >> 4);
  unsigned short o[8];
#pragma unroll
  for (int i = 0; i < 8; ++i) {
    int k = k0 + i;
    float v = (k < K) ? src[n * K + k] : 0.f;
    o[i] = f2bf(v);
  }
  *(uint4v*)(dst + (size_t)tid * 8) = *(const uint4v*)o;
}

// Build x0 (concat cont feats + embeddings), bf16, A-fragment order over 32
// 16-row batch tiles, K padded 22->32.
__global__ void pack_x0_kern(const float* __restrict__ xc, const int* __restrict__ idxs,
                             const int* __restrict__ idxi, const float* __restrict__ es,
                             const float* __restrict__ ei, unsigned short* __restrict__ dst) {
  int tid = blockIdx.x * 256 + threadIdx.x;
  if (tid >= TT * 32 * 64) return;
  int l = tid & 63;
  int b = (tid >> 6) & 31;
  int t = tid >> 11;
  int bi = b * 16 + (l & 15);
  int k0 = 8 * (l >> 4);
  int si = idxs[bi * TT + t];
  int it = idxi[bi * TT + t];
  const float* xr = xc + ((size_t)bi * TT + t) * 12;
  unsigned short o[8];
#pragma unroll
  for (int i = 0; i < 8; ++i) {
    int k = k0 + i;
    float v;
    if (k < 12)      v = xr[k];
    else if (k < 17) v = es[si * 5 + (k - 12)];
    else if (k < 22) v = ei[it * 5 + (k - 17)];
    else             v = 0.f;
    o[i] = f2bf(v);
  }
  *(uint4v*)(dst + (size_t)tid * 8) = *(const uint4v*)o;
}

// Gaussian head for one step; reads compact h2 slot [4][RSTR]. Wave 0 only.
__device__ __forceinline__ void head_step(
    int b, int t, const unsigned short* slotbase,
    const float* wmS, const float* waS, const float* vS,
    float bmv, float bav, float* out) {
  const int tid = threadIdx.x;
  if (tid >= 64) return;
  int s_ = tid & 7, hd = (tid >> 3) & 1, bi = tid >> 4;  // bi 0..3
  const float* wv = hd ? waS : wmS;
  const uint4v* hp = (const uint4v*)(slotbase + bi * RSTR + s_ * 16);
  uint4v q0 = hp[0], q1 = hp[1];
  const f32x4* wp4 = (const f32x4*)(wv + s_ * 16);
  f32x4 w0 = wp4[0], w1 = wp4[1], w2 = wp4[2], w3 = wp4[3];
  float part = 0.f;
  part += __uint_as_float(q0[0] << 16) * w0[0];
  part += __uint_as_float(q0[0] & 0xffff0000u) * w0[1];
  part += __uint_as_float(q0[1] << 16) * w0[2];
  part += __uint_as_float(q0[1] & 0xffff0000u) * w0[3];
  part += __uint_as_float(q0[2] << 16) * w1[0];
  part += __uint_as_float(q0[2] & 0xffff0000u) * w1[1];
  part += __uint_as_float(q0[3] << 16) * w1[2];
  part += __uint_as_float(q0[3] & 0xffff0000u) * w1[3];
  part += __uint_as_float(q1[0] << 16) * w2[0];
  part += __uint_as_float(q1[0] & 0xffff0000u) * w2[1];
  part += __uint_as_float(q1[1] << 16) * w2[2];
  part += __uint_as_float(q1[1] & 0xffff0000u) * w2[3];
  part += __uint_as_float(q1[2] << 16) * w3[0];
  part += __uint_as_float(q1[2] & 0xffff0000u) * w3[1];
  part += __uint_as_float(q1[3] << 16) * w3[2];
  part += __uint_as_float(q1[3] & 0xffff0000u) * w3[3];
  part += __shfl_xor(part, 1);
  part += __shfl_xor(part, 2);
  part += __shfl_xor(part, 4);
  if (s_ == 0) {
    float val = part + (hd ? bav : bmv);
    if (hd) val = softplus_(val);
    out[(((size_t)(b * 4 + bi)) * TT + t) * 2 + hd] = val * vS[bi];
  }
}

// One layer's scan over one chunk. Weights AGPR-resident. gx lookahead:
// gx(t) = bias + X(t)*Wih computed 2 steps early into rotating gA/gB (named
// regs, rule-20). Post-barrier chain = ah read + 16 hh-MFMAs + select + trans.
// No shuffles: row-duplicated A makes every lane group's acc identical, so
// each lane selects its (r_, j) cell from its OWN acc registers.
template<int L>
__device__ __forceinline__ void scan_chunk(
    int k, int b, const unsigned short* wp_ih, const unsigned short* wp_hh,
    const unsigned short* x0p, const unsigned short* inb, unsigned short* outb,
    unsigned short* carry, float& cc, const float (&bia)[4],
    const float* wmS, const float* waS, const float* vS,
    float bmv, float bav, float* out) {
  const int tid = threadIdx.x;
  const int l = tid & 63;
  const int w = tid >> 6;  // wave 0..7
  const int j = w * 16 + (l & 15);
  const int afrag = (l & 3) * RSTR + 8 * (l >> 4);  // + c*32 per k-tile (dup rows)
  const int xlane = (l & 48) | ((b & 3) * 4 + (l & 3));
  const int r_ = l >> 4;

  // -------- weight burst into AGPRs (2 wait-groups: ih, hh) --------
  uint4v ihf[4][4], hhf[4][4];
  if (L == 0) {
#pragma unroll
    for (int g = 0; g < 4; ++g)
      ihf[g][0] = pin_a(wp_ih + ((size_t)(g * 8 + w) * 64 + l) * 8);
  } else {
#pragma unroll
    for (int g = 0; g < 4; ++g)
#pragma unroll
      for (int c = 0; c < 4; ++c)
        ihf[g][c] = pin_a(wp_ih + ((size_t)((g * 8 + w) * 4 + c) * 64 + l) * 8);
  }
  __builtin_amdgcn_sched_barrier(0);
#pragma unroll
  for (int g = 0; g < 4; ++g)
#pragma unroll
    for (int c = 0; c < 4; ++c)
      hhf[g][c] = pin_a(wp_hh + ((size_t)((g * 8 + w) * 4 + c) * 64 + l) * 8);
  __builtin_amdgcn_sched_barrier(0);
  asm volatile("s_nop 1");  // accvgpr_write -> MFMA B-read wait states

  f32x4 gA[4], gB[4];

  // compute gx(TT_) = bias + X(TT_)*Wih into G (stable inputs, off-chain)
#define CALCGX(TT_, G)                                                          \
  do {                                                                          \
    _Pragma("unroll")                                                           \
    for (int g = 0; g < 4; ++g) {                                               \
      float bb = bia[g];                                                        \
      f32x4 z = {bb, bb, bb, bb};                                               \
      G[g] = z;                                                                 \
    }                                                                           \
    if (L == 0) {                                                               \
      uint4v xf = *(const uint4v*)(x0p +                                        \
          (((size_t)(k * CH + (TT_)) * 32 + (b >> 2)) * 64 + xlane) * 8);       \
      _Pragma("unroll")                                                         \
      for (int g = 0; g < 4; ++g) mfma_va(G[g], xf, ihf[g][0]);                 \
    } else {                                                                    \
      uint4v inF[4];                                                            \
      _Pragma("unroll")                                                         \
      for (int c = 0; c < 4; ++c)                                               \
        inF[c] = *(const uint4v*)(inb + (TT_) * SLOT + afrag + c * 32);         \
      _Pragma("unroll")                                                         \
      for (int c = 0; c < 4; ++c)                                               \
        for (int g = 0; g < 4; ++g) mfma_va(G[g], inF[c], ihf[g][c]);           \
    }                                                                           \
  } while (0)

#define STEP(TT_, G)                                                            \
  do {                                                                          \
    const int t = k * CH + (TT_);                                               \
    BAR();                                                                      \
    if (L == 2 && (TT_) > 0)                                                    \
      head_step(b, t - 1, outb + ((TT_)-1) * SLOT, wmS, waS, vS, bmv, bav, out);\
    const unsigned short* ahb = ((TT_) == 0) ? carry : outb + ((TT_)-1) * SLOT; \
    uint4v ah[4];                                                               \
    _Pragma("unroll")                                                           \
    for (int c = 0; c < 4; ++c) ah[c] = *(const uint4v*)(ahb + afrag + c * 32); \
    _Pragma("unroll")                                                           \
    for (int c = 0; c < 4; ++c)                                                 \
      for (int g = 0; g < 4; ++g) {                                             \
        if (c == 3) mfma_va_end(G[g], ah[c], hhf[g][c]);  /* fused s_nop 7 */   \
        else        mfma_va(G[g], ah[c], hhf[g][c]);                            \
      }                                                                         \
    float gv[4];                                                                \
    _Pragma("unroll")                                                           \
    for (int g = 0; g < 4; ++g) {                                               \
      float va = (r_ & 1) ? G[g][1] : G[g][0];                                  \
      float vb = (r_ & 1) ? G[g][3] : G[g][2];                                  \
      gv[g] = (r_ & 2) ? vb : va;                                               \
    }                                                                           \
    float ig = sigm(gv[0]);                                                     \
    float fg = sigm(gv[1]);                                                     \
    float gt = tanh_(gv[2]);                                                    \
    float og = sigm(gv[3]);                                                     \
    cc = fg * cc + ig * gt;                                                     \
    float h = og * tanh_(cc);                                                   \
    unsigned short hb = f2bf(h);                                                \
    outb[(TT_) * SLOT + r_ * RSTR + j] = hb;                                    \
    if ((TT_) == CH - 1) carry[r_ * RSTR + j] = hb;                             \
    if ((TT_) + 2 < CH) CALCGX((TT_) + 2, G);  /* refill into freed regs */     \
  } while (0)

  CALCGX(0, gA);
  CALCGX(1, gB);
  for (int tt = 0; tt < CH; tt += 2) {
    STEP(tt, gA);
    STEP(tt + 1, gB);
  }
#undef STEP
#undef CALCGX
  if (L == 2) {
    BAR();
    head_step(b, k * CH + CH - 1, outb + (CH - 1) * SLOT, wmS, waS, vS, bmv, bav, out);
  }
}

__attribute__((amdgpu_waves_per_eu(2, 2)))  // cap 2 waves/SIMD -> 256-reg budget
__global__ void __launch_bounds__(NTHREADS)
lstm_seq4_kern(
    const unsigned short* __restrict__ wp_ih0, const unsigned short* __restrict__ wp_hh0,
    const unsigned short* __restrict__ wp_ih1, const unsigned short* __restrict__ wp_hh1,
    const unsigned short* __restrict__ wp_ih2, const unsigned short* __restrict__ wp_hh2,
    const unsigned short* __restrict__ x0p,
    const float* __restrict__ b0, const float* __restrict__ b1, const float* __restrict__ b2,
    const float* __restrict__ Wm, const float* __restrict__ bm,
    const float* __restrict__ Wa, const float* __restrict__ ba,
    const float* __restrict__ v, float* __restrict__ out) {
  __shared__ __align__(16) unsigned short bufS[2][CH * SLOT];  // ping-pong (72 KB)
  __shared__ __align__(16) unsigned short carryS[3 * SLOT];    // per-layer h carry
  __shared__ __align__(16) float wmS[128], waS[128];
  __shared__ float vS[4];

  const int tid = threadIdx.x;
  const int b = blockIdx.x;      // 0..127, batch rows [b*4, b*4+4)
  const int l = tid & 63;
  const int w = tid >> 6;
  const int j = w * 16 + (l & 15);

  for (int i = tid; i < 3 * SLOT; i += NTHREADS) carryS[i] = 0;
  if (tid < 128) { wmS[tid] = Wm[tid]; waS[tid] = Wa[tid]; }
  if (tid < 4) vS[tid] = v[b * 4 + tid];

  float bia0[4], bia1[4], bia2[4];
#pragma unroll
  for (int g = 0; g < 4; ++g) {
    bia0[g] = b0[g * 128 + j];
    bia1[g] = b1[g * 128 + j];
    bia2[g] = b2[g * 128 + j];
  }
  float cc0 = 0.f, cc1 = 0.f, cc2 = 0.f;
  const float bmv = bm[0], bav = ba[0];

  // Laundered weight base pointers: block LICM of bursts out of the chunk loop.
  size_t p_ih0 = (size_t)wp_ih0, p_hh0 = (size_t)wp_hh0;
  size_t p_ih1 = (size_t)wp_ih1, p_hh1 = (size_t)wp_hh1;
  size_t p_ih2 = (size_t)wp_ih2, p_hh2 = (size_t)wp_hh2;

  __syncthreads();

  for (int k = 0; k < NCH; ++k) {
    asm volatile("" : "+s"(p_ih0), "+s"(p_hh0), "+s"(p_ih1), "+s"(p_hh1),
                      "+s"(p_ih2), "+s"(p_hh2));
    scan_chunk<0>(k, b, (const unsigned short*)p_ih0, (const unsigned short*)p_hh0,
                  x0p, nullptr, bufS[0], carryS, cc0, bia0, wmS, waS, vS, bmv, bav, out);
    scan_chunk<1>(k, b, (const unsigned short*)p_ih1, (const unsigned short*)p_hh1,
                  x0p, bufS[0], bufS[1], carryS + SLOT, cc1, bia1,
                  wmS, waS, vS, bmv, bav, out);
    scan_chunk<2>(k, b, (const unsigned short*)p_ih2, (const unsigned short*)p_hh2,
                  x0p, bufS[1], bufS[0], carryS + 2 * SLOT, cc2, bia2,
                  wmS, waS, vS, bmv, bav, out);
  }
}

extern "C" void kernel_launch(void* const* d_in, const int* in_sizes, int n_in,
                              void* d_out, int out_size, void* d_ws, size_t ws_size,
                              hipStream_t stream) {
  const float* x_cont    = (const float*)d_in[0];
  const int*   idx_shops = (const int*)d_in[1];
  const int*   idx_items = (const int*)d_in[2];
  const float* v         = (const float*)d_in[3];
  const float* emb_shops = (const float*)d_in[4];
  const float* emb_items = (const float*)d_in[5];
  const float* Wih0 = (const float*)d_in[6];
  const float* Whh0 = (const float*)d_in[7];
  const float* b0   = (const float*)d_in[8];
  const float* Wih1 = (const float*)d_in[9];
  const float* Whh1 = (const float*)d_in[10];
  const float* b1   = (const float*)d_in[11];
  const float* Wih2 = (const float*)d_in[12];
  const float* Whh2 = (const float*)d_in[13];
  const float* b2   = (const float*)d_in[14];
  const float* Wm   = (const float*)d_in[15];
  const float* bm   = (const float*)d_in[16];
  const float* Wa   = (const float*)d_in[17];
  const float* ba   = (const float*)d_in[18];
  float* out = (float*)d_out;

  unsigned short* ws = (unsigned short*)d_ws;
  unsigned short* wp_ih0 = ws;                  // 32*1*64*8   = 16384 el
  unsigned short* wp_hh0 = wp_ih0 + 16384;      // 32*4*64*8   = 65536 el
  unsigned short* wp_ih1 = wp_hh0 + 65536;
  unsigned short* wp_hh1 = wp_ih1 + 65536;
  unsigned short* wp_ih2 = wp_hh1 + 65536;
  unsigned short* wp_hh2 = wp_ih2 + 65536;
  unsigned short* x0p    = wp_hh2 + 65536;      // 512*32*64*8 = 8388608 el (17.5 MB total)

  pack_w_kern<<<8, 256, 0, stream>>>(Wih0, wp_ih0, 22, 1);
  pack_w_kern<<<32, 256, 0, stream>>>(Whh0, wp_hh0, 128, 4);
  pack_w_kern<<<32, 256, 0, stream>>>(Wih1, wp_ih1, 128, 4);
  pack_w_kern<<<32, 256, 0, stream>>>(Whh1, wp_hh1, 128, 4);
  pack_w_kern<<<32, 256, 0, stream>>>(Wih2, wp_ih2, 128, 4);
  pack_w_kern<<<32, 256, 0, stream>>>(Whh2, wp_hh2, 128, 4);
  pack_x0_kern<<<4096, 256, 0, stream>>>(x_cont, idx_shops, idx_items,
                                         emb_shops, emb_items, x0p);
  lstm_seq4_kern<<<NWGS, NTHREADS, 0, stream>>>(wp_ih0, wp_hh0, wp_ih1, wp_hh1,
                                                wp_ih2, wp_hh2, x0p,
                                                b0, b1, b2, Wm, bm, Wa, ba, v, out);
}

// Round 16
// 831.098 us; speedup vs baseline: 2.5526x; 1.6530x over previous
//
#include <hip/hip_runtime.h>
#include <hip/hip_bf16.h>

#define NB 512
#define TT 512
#define NTILE 64       // 64 tiles x 8 batch rows
#define NTHREADS 512   // 8 waves
#define CH 16          // steps per chunk (ring granularity)
#define NCH 32         // 512/16
#define RSTR 144       // h row stride in LDS (288B)
#define HSLOT (8 * RSTR)

typedef float f32x4 __attribute__((ext_vector_type(4)));
typedef unsigned int uint4v __attribute__((ext_vector_type(4)));
typedef unsigned int uint2v __attribute__((ext_vector_type(2)));

// Raw barrier: LDS drain only; global loads/stores stay in flight.
#define BAR() asm volatile("s_waitcnt lgkmcnt(0)\n\ts_barrier" ::: "memory")

__device__ __forceinline__ unsigned short f2bf(float f) {
  unsigned int u = __float_as_uint(f);
  u = u + 0x7FFFu + ((u >> 16) & 1u);
  return (unsigned short)(u >> 16);
}
__device__ __forceinline__ unsigned int pk2(float lo, float hi) {
  return ((unsigned int)f2bf(hi) << 16) | (unsigned int)f2bf(lo);
}
__device__ __forceinline__ float sigm(float x) {
  return __builtin_amdgcn_rcpf(1.f + __builtin_amdgcn_exp2f(-1.44269504f * x));
}
__device__ __forceinline__ float tanh_(float x) {
  return 1.f - 2.f * __builtin_amdgcn_rcpf(1.f + __builtin_amdgcn_exp2f(2.88539008f * x));
}
__device__ __forceinline__ float softplus_(float x) {
  if (x > 15.f) return x;
  float e = __builtin_amdgcn_exp2f(1.44269504f * x);
  return 0.69314718f * __builtin_amdgcn_logf(1.f + e);
}
__device__ __forceinline__ uint4v pin_a(const unsigned short* p) {
  uint4v u = *(const uint4v*)p;
  asm volatile("" : "+a"(u));
  return u;
}
__device__ __forceinline__ void mfma_va(f32x4& acc, uint4v a, uint4v b) {
  asm volatile("v_mfma_f32_16x16x32_bf16 %0, %1, %2, %0" : "+v"(acc) : "v"(a), "a"(b));
}
__device__ __forceinline__ void mfma_va_end(f32x4& acc, uint4v a, uint4v b) {
  asm volatile("v_mfma_f32_16x16x32_bf16 %0, %1, %2, %0\n\ts_nop 7"
               : "+v"(acc) : "v"(a), "a"(b));
}

// Pack a [512][K] f32 weight matrix into bf16 B-fragment order.
__global__ void pack_w_kern(const float* __restrict__ src, unsigned short* __restrict__ dst,
                            int K, int ktiles) {
  int tid = blockIdx.x * 256 + threadIdx.x;
  int total = 32 * ktiles * 64;
  if (tid >= total) return;
  int l = tid & 63;
  int c = (tid >> 6) % ktiles;
  int tau = tid / (64 * ktiles);
  int n = tau * 16 + (l & 15);
  int k0 = c * 32 + 8 * (l >> 4);
  unsigned short o[8];
#pragma unroll
  for (int i = 0; i < 8; ++i) {
    int k = k0 + i;
    float v = (k < K) ? src[n * K + k] : 0.f;
    o[i] = f2bf(v);
  }
  *(uint4v*)(dst + (size_t)tid * 8) = *(const uint4v*)o;
}

// Pre-gather embeddings per (bi,t): 12 bf16 {es0..4, ei0..4, 0, 0}.
__global__ void pack_emb_kern(const int* __restrict__ idxs, const int* __restrict__ idxi,
                              const float* __restrict__ es, const float* __restrict__ ei,
                              unsigned short* __restrict__ embp) {
  int tid = blockIdx.x * 256 + threadIdx.x;
  if (tid >= NB * TT) return;
  int si = idxs[tid], it = idxi[tid];
  unsigned int u[6];
  u[0] = pk2(es[si * 5 + 0], es[si * 5 + 1]);
  u[1] = pk2(es[si * 5 + 2], es[si * 5 + 3]);
  u[2] = pk2(es[si * 5 + 4], ei[it * 5 + 0]);
  u[3] = pk2(ei[it * 5 + 1], ei[it * 5 + 2]);
  u[4] = pk2(ei[it * 5 + 3], ei[it * 5 + 4]);
  u[5] = 0;
  uint2v* d = (uint2v*)(embp + (size_t)tid * 12);
  uint2v a = {u[0], u[1]}, b = {u[2], u[3]}, c = {u[4], u[5]};
  d[0] = a; d[1] = b; d[2] = c;
}

// Prefetch input for step (k,tt): L0 raw x/emb words; L>0 ring A-fragments.
template<int L>
__device__ __forceinline__ void pref_in(int tl, int k, int tt, int l,
    const float* xc, const unsigned short* embp, const unsigned short* ring_in,
    uint4v (&pf)[4]) {
  if (L == 0) {
    const int g4 = l >> 4;
    const int bi = tl * 8 + (l & 7);
    const int t = k * CH + tt;
    const float* xb = xc + ((size_t)bi * TT + t) * 12;
    const unsigned int* ep = (const unsigned int*)(embp + ((size_t)bi * TT + t) * 12);
    if (g4 == 0) {
      pf[0] = *(const uint4v*)xb;
      pf[1] = *(const uint4v*)(xb + 4);
    } else if (g4 == 1) {
      pf[0] = *(const uint4v*)(xb + 8);
      pf[1][0] = ep[0];
      pf[1][1] = ep[1];
    } else if (g4 == 2) {
      pf[0][0] = ep[2]; pf[0][1] = ep[3]; pf[0][2] = ep[4]; pf[0][3] = ep[5];
    }
  } else {
    const unsigned short* base = ring_in + (((size_t)(k & 1) * CH + tt) * 1024);
    const int off = (l & 7) * 128 + 8 * (l >> 4);
#pragma unroll
    for (int c = 0; c < 4; ++c)
      pf[c] = *(const uint4v*)(base + off + c * 32);
  }
}

// Assemble L0's x A-fragment (row = l&7, k0 = 8*(l>>4), K padded 22->32).
__device__ __forceinline__ uint4v asm_x(int l, const uint4v (&pf)[4]) {
  uint4v r = {0, 0, 0, 0};
  const int g4 = l >> 4;
  if (g4 == 0) {
    r[0] = pk2(__uint_as_float(pf[0][0]), __uint_as_float(pf[0][1]));
    r[1] = pk2(__uint_as_float(pf[0][2]), __uint_as_float(pf[0][3]));
    r[2] = pk2(__uint_as_float(pf[1][0]), __uint_as_float(pf[1][1]));
    r[3] = pk2(__uint_as_float(pf[1][2]), __uint_as_float(pf[1][3]));
  } else if (g4 == 1) {
    r[0] = pk2(__uint_as_float(pf[0][0]), __uint_as_float(pf[0][1]));
    r[1] = pk2(__uint_as_float(pf[0][2]), __uint_as_float(pf[0][3]));
    r[2] = pf[1][0];
    r[3] = pf[1][1];
  } else if (g4 == 2) {
    r = pf[0];
  }
  return r;
}

// gx = X*Wih into G (zero-seeded; bias folded at epilogue). Off the h-chain.
template<int L>
__device__ __forceinline__ void calc_gx(int l, const uint4v (&pf)[4],
                                        uint4v (&ihf)[4][4], f32x4 (&G)[4]) {
#pragma unroll
  for (int g = 0; g < 4; ++g) { f32x4 z = {0.f, 0.f, 0.f, 0.f}; G[g] = z; }
  if (L == 0) {
    uint4v xf = asm_x(l, pf);
#pragma unroll
    for (int g = 0; g < 4; ++g) mfma_va(G[g], xf, ihf[g][0]);
  } else {
#pragma unroll
    for (int c = 0; c < 4; ++c)
#pragma unroll
      for (int g = 0; g < 4; ++g) mfma_va(G[g], pf[c], ihf[g][c]);
  }
}

// Gaussian head for 8 rows; 128 threads (waves 0-1). Stage 2 only.
__device__ __forceinline__ void head_step8(
    int tl, int t, const unsigned short* hb,
    const float* wmS, const float* waS, const float* vS,
    float bmv, float bav, float* out) {
  const int tid = threadIdx.x;
  if (tid >= 128) return;
  int s_ = tid & 7, hd = (tid >> 3) & 1, bi = tid >> 4;  // bi 0..7
  const float* wv = hd ? waS : wmS;
  const uint4v* hp = (const uint4v*)(hb + bi * RSTR + s_ * 16);
  uint4v q0 = hp[0], q1 = hp[1];
  const f32x4* wp4 = (const f32x4*)(wv + s_ * 16);
  f32x4 w0 = wp4[0], w1 = wp4[1], w2 = wp4[2], w3 = wp4[3];
  float part = 0.f;
  part += __uint_as_float(q0[0] << 16) * w0[0];
  part += __uint_as_float(q0[0] & 0xffff0000u) * w0[1];
  part += __uint_as_float(q0[1] << 16) * w0[2];
  part += __uint_as_float(q0[1] & 0xffff0000u) * w0[3];
  part += __uint_as_float(q0[2] << 16) * w1[0];
  part += __uint_as_float(q0[2] & 0xffff0000u) * w1[1];
  part += __uint_as_float(q0[3] << 16) * w1[2];
  part += __uint_as_float(q0[3] & 0xffff0000u) * w1[3];
  part += __uint_as_float(q1[0] << 16) * w2[0];
  part += __uint_as_float(q1[0] & 0xffff0000u) * w2[1];
  part += __uint_as_float(q1[1] << 16) * w2[2];
  part += __uint_as_float(q1[1] & 0xffff0000u) * w2[3];
  part += __uint_as_float(q1[2] << 16) * w3[0];
  part += __uint_as_float(q1[2] & 0xffff0000u) * w3[1];
  part += __uint_as_float(q1[3] << 16) * w3[2];
  part += __uint_as_float(q1[3] & 0xffff0000u) * w3[3];
  part += __shfl_xor(part, 1);
  part += __shfl_xor(part, 2);
  part += __shfl_xor(part, 4);
  if (s_ == 0) {
    float val = part + (hd ? bav : bmv);
    if (hd) val = softplus_(val);
    out[(((size_t)(tl * 8 + bi)) * TT + t) * 2 + hd] = val * vS[bi];
  }
}

// One recurrence step. Post-barrier chain: ah read + 16 hh-MFMAs + selects +
// trans + h write. 8-row dup: every lane's acc is a valid copy; cell pick via
// own-register selects (no shuffles). cc0/cc1 = this lane's 2 cell states.
template<int L>
__device__ __forceinline__ void step_core(
    int tl, int t, int tt, int k, unsigned short* hbuf, unsigned short* ring_out,
    uint4v (&hhf)[4][4], f32x4 (&G)[4], float& cc0, float& cc1,
    const float (&bia)[4], const float* wmS, const float* waS, const float* vS,
    float bmv, float bav, float* out) {
  const int tid = threadIdx.x;
  const int l = tid & 63;
  const int w = tid >> 6;
  unsigned short* hb_prev = hbuf + (((t - 1) & 1) ? HSLOT : 0);
  unsigned short* hb_cur  = hbuf + ((t & 1) ? HSLOT : 0);
  BAR();  // h(t-1) visible; all reads of slot (t&1) drained
  if (L == 2 && t > 0)
    head_step8(tl, t - 1, hb_prev, wmS, waS, vS, bmv, bav, out);
  if (L < 2 && tt > 0) {
    // flush h(t-1) -> ring slot tt-1 (fire-and-forget; drained at chunk end)
    if (tid < 128) {
      int row = tid >> 4, seg = tid & 15;
      uint4v q = *(const uint4v*)(hb_prev + row * RSTR + seg * 8);
      *(uint4v*)(ring_out + (((size_t)(k & 1) * CH + (tt - 1)) * 1024) + row * 128 + seg * 8) = q;
    }
  }
  const int afrag = (l & 7) * RSTR + 8 * (l >> 4);
  uint4v ah[4];
#pragma unroll
  for (int c = 0; c < 4; ++c) ah[c] = *(const uint4v*)(hb_prev + afrag + c * 32);
#pragma unroll
  for (int c = 0; c < 4; ++c)
#pragma unroll
    for (int g = 0; g < 4; ++g) {
      if (c == 3) mfma_va_end(G[g], ah[c], hhf[g][c]);  // fused s_nop 7
      else        mfma_va(G[g], ah[c], hhf[g][c]);
    }
  const int rsel = (l >> 5) & 1;                    // 0 -> regs {0,1}, 1 -> {2,3}
  const int row0 = ((l >> 4) & 1) * 4 + rsel * 2;   // this lane's 2 rows
  const int j = w * 16 + (l & 15);
  float gv0[4], gv1[4];
#pragma unroll
  for (int g = 0; g < 4; ++g) {
    gv0[g] = (rsel ? G[g][2] : G[g][0]) + bia[g];
    gv1[g] = (rsel ? G[g][3] : G[g][1]) + bia[g];
  }
  {
    float ig = sigm(gv0[0]), fg = sigm(gv0[1]), gt = tanh_(gv0[2]), og = sigm(gv0[3]);
    cc0 = fg * cc0 + ig * gt;
    hb_cur[row0 * RSTR + j] = f2bf(og * tanh_(cc0));
  }
  {
    float ig = sigm(gv1[0]), fg = sigm(gv1[1]), gt = tanh_(gv1[2]), og = sigm(gv1[3]);
    cc1 = fg * cc1 + ig * gt;
    hb_cur[(row0 + 1) * RSTR + j] = f2bf(og * tanh_(cc1));
  }
}

template<int L>
__device__ __forceinline__ void stage_body(
    int tl, const unsigned short* wp_ih, const unsigned short* wp_hh,
    const float* xc, const unsigned short* embp,
    const unsigned short* ring_in, unsigned short* ring_out,
    int* pub_in, int* cons_in, int* pub_out, int* cons_out,
    unsigned short* hbuf, float* wmS, float* waS, float* vS,
    const float* bvec, const float* Wm, const float* bm,
    const float* Wa, const float* ba, const float* v, float* out) {
  const int tid = threadIdx.x;
  const int l = tid & 63;
  const int w = tid >> 6;

  for (int i = tid; i < 2 * HSLOT; i += NTHREADS) hbuf[i] = 0;
  if (L == 2) {
    if (tid < 128) { wmS[tid] = Wm[tid]; waS[tid] = Wa[tid]; }
    if (tid < 8) vS[tid] = v[tl * 8 + tid];
  }
  // -------- weight burst into AGPRs (resident for entire kernel) --------
  uint4v ihf[4][4], hhf[4][4];
  if (L == 0) {
#pragma unroll
    for (int g = 0; g < 4; ++g)
      ihf[g][0] = pin_a(wp_ih + ((size_t)(g * 8 + w) * 64 + l) * 8);
  } else {
#pragma unroll
    for (int g = 0; g < 4; ++g)
#pragma unroll
      for (int c = 0; c < 4; ++c)
        ihf[g][c] = pin_a(wp_ih + ((size_t)((g * 8 + w) * 4 + c) * 64 + l) * 8);
  }
  __builtin_amdgcn_sched_barrier(0);
#pragma unroll
  for (int g = 0; g < 4; ++g)
#pragma unroll
    for (int c = 0; c < 4; ++c)
      hhf[g][c] = pin_a(wp_hh + ((size_t)((g * 8 + w) * 4 + c) * 64 + l) * 8);
  __builtin_amdgcn_sched_barrier(0);
  asm volatile("s_nop 1");  // accvgpr_write -> MFMA B-read wait states

  const int j = w * 16 + (l & 15);
  float bia[4];
#pragma unroll
  for (int g = 0; g < 4; ++g) bia[g] = bvec[g * 128 + j];
  float cc0 = 0.f, cc1 = 0.f;
  float bmv = 0.f, bav = 0.f;
  if (L == 2) { bmv = bm[0]; bav = ba[0]; }

  uint4v pfA[4], pfB[4];
  f32x4 GA[4], GB[4];
  __syncthreads();

  for (int k = 0; k < NCH; ++k) {
    if (tid == 0) {
      if (L > 0) {
        while (__hip_atomic_load(pub_in, __ATOMIC_RELAXED, __HIP_MEMORY_SCOPE_AGENT) < k + 1)
          __builtin_amdgcn_s_sleep(16);
        (void)__hip_atomic_load(pub_in, __ATOMIC_ACQUIRE, __HIP_MEMORY_SCOPE_AGENT);
      }
      if (L < 2 && k >= 2) {
        while (__hip_atomic_load(cons_out, __ATOMIC_RELAXED, __HIP_MEMORY_SCOPE_AGENT) < k - 1)
          __builtin_amdgcn_s_sleep(16);
      }
    }
    __syncthreads();  // flag visibility + cache-inv ordering for all threads
    pref_in<L>(tl, k, 0, l, xc, embp, ring_in, pfA);
    pref_in<L>(tl, k, 1, l, xc, embp, ring_in, pfB);
    calc_gx<L>(l, pfA, ihf, GA);  // gx for step 0 (once-per-chunk stall, ok)
    for (int tt = 0; tt < CH; tt += 2) {
      const int t = k * CH + tt;
      step_core<L>(tl, t, tt, k, hbuf, ring_out, hhf, GA, cc0, cc1, bia,
                   wmS, waS, vS, bmv, bav, out);
      if (tt + 2 < CH) pref_in<L>(tl, k, tt + 2, l, xc, embp, ring_in, pfA);
      calc_gx<L>(l, pfB, ihf, GB);  // gx for step tt+1 (barrier shadow)
      step_core<L>(tl, t + 1, tt + 1, k, hbuf, ring_out, hhf, GB, cc0, cc1, bia,
                   wmS, waS, vS, bmv, bav, out);
      if (tt + 3 < CH) pref_in<L>(tl, k, tt + 3, l, xc, embp, ring_in, pfB);
      if (tt + 2 < CH) calc_gx<L>(l, pfA, ihf, GA);  // gx for step tt+2
    }
    BAR();  // h(chunk-last) visible
    if (L < 2) {
      if (tid < 128) {
        int row = tid >> 4, seg = tid & 15;
        const unsigned short* hb = hbuf + (((k * CH + CH - 1) & 1) ? HSLOT : 0);
        uint4v q = *(const uint4v*)(hb + row * RSTR + seg * 8);
        *(uint4v*)(ring_out + (((size_t)(k & 1) * CH + (CH - 1)) * 1024) + row * 128 + seg * 8) = q;
      }
    }
    __syncthreads();  // drains vmcnt: all ring stores in L2 before release
    if (tid == 0) {
      if (L < 2)
        __hip_atomic_store(pub_out, k + 1, __ATOMIC_RELEASE, __HIP_MEMORY_SCOPE_AGENT);
      if (L > 0)
        __hip_atomic_store(cons_in, k + 1, __ATOMIC_RELEASE, __HIP_MEMORY_SCOPE_AGENT);
    }
  }
  if (L == 2) {
    BAR();
    const unsigned short* hb = hbuf + (((TT - 1) & 1) ? HSLOT : 0);
    head_step8(tl, TT - 1, hb, wmS, waS, vS, bmv, bav, out);
  }
}

__attribute__((amdgpu_waves_per_eu(2, 2)))
__global__ void __launch_bounds__(NTHREADS)
lstm_pipe3_kern(
    const unsigned short* wp_ih0, const unsigned short* wp_hh0,
    const unsigned short* wp_ih1, const unsigned short* wp_hh1,
    const unsigned short* wp_ih2, const unsigned short* wp_hh2,
    const float* xc, const unsigned short* embp,
    unsigned short* ring0, unsigned short* ring1, int* flags,
    const float* b0, const float* b1, const float* b2,
    const float* Wm, const float* bm, const float* Wa, const float* ba,
    const float* v, float* out) {
  __shared__ __align__(16) unsigned short hbuf[2 * HSLOT];
  __shared__ __align__(16) float wmS[128], waS[128];
  __shared__ float vS[8];
  const int layer = blockIdx.x >> 6;  // 0..2
  const int tl = blockIdx.x & 63;     // 0..63
  int* f = flags + tl * 4;            // [pub0, cons0, pub1, cons1]
  unsigned short* r0 = ring0 + (size_t)tl * (2 * CH * 1024);
  unsigned short* r1 = ring1 + (size_t)tl * (2 * CH * 1024);
  if (layer == 0)
    stage_body<0>(tl, wp_ih0, wp_hh0, xc, embp, nullptr, r0,
                  nullptr, nullptr, f + 0, f + 1, hbuf, wmS, waS, vS,
                  b0, Wm, bm, Wa, ba, v, out);
  else if (layer == 1)
    stage_body<1>(tl, wp_ih1, wp_hh1, nullptr, nullptr, r0, r1,
                  f + 0, f + 1, f + 2, f + 3, hbuf, wmS, waS, vS,
                  b1, Wm, bm, Wa, ba, v, out);
  else
    stage_body<2>(tl, wp_ih2, wp_hh2, nullptr, nullptr, r1, nullptr,
                  f + 2, f + 3, nullptr, nullptr, hbuf, wmS, waS, vS,
                  b2, Wm, bm, Wa, ba, v, out);
}

extern "C" void kernel_launch(void* const* d_in, const int* in_sizes, int n_in,
                              void* d_out, int out_size, void* d_ws, size_t ws_size,
                              hipStream_t stream) {
  const float* x_cont    = (const float*)d_in[0];
  const int*   idx_shops = (const int*)d_in[1];
  const int*   idx_items = (const int*)d_in[2];
  const float* v         = (const float*)d_in[3];
  const float* emb_shops = (const float*)d_in[4];
  const float* emb_items = (const float*)d_in[5];
  const float* Wih0 = (const float*)d_in[6];
  const float* Whh0 = (const float*)d_in[7];
  const float* b0   = (const float*)d_in[8];
  const float* Wih1 = (const float*)d_in[9];
  const float* Whh1 = (const float*)d_in[10];
  const float* b1   = (const float*)d_in[11];
  const float* Wih2 = (const float*)d_in[12];
  const float* Whh2 = (const float*)d_in[13];
  const float* b2   = (const float*)d_in[14];
  const float* Wm   = (const float*)d_in[15];
  const float* bm   = (const float*)d_in[16];
  const float* Wa   = (const float*)d_in[17];
  const float* ba   = (const float*)d_in[18];
  float* out = (float*)d_out;

  char* wsb = (char*)d_ws;
  int* flags = (int*)wsb;                              // 1 KB used
  unsigned short* wp_ih0 = (unsigned short*)(wsb + 4096);
  unsigned short* wp_hh0 = wp_ih0 + 16384;
  unsigned short* wp_ih1 = wp_hh0 + 65536;
  unsigned short* wp_hh1 = wp_ih1 + 65536;
  unsigned short* wp_ih2 = wp_hh1 + 65536;
  unsigned short* wp_hh2 = wp_ih2 + 65536;
  unsigned short* embp   = wp_hh2 + 65536;             // 512*512*12 = 3,145,728
  unsigned short* ring0  = embp + 3145728;             // 64*2*16*1024 = 2,097,152
  unsigned short* ring1  = ring0 + 2097152;            // total ~15.4 MB (proven window)

  hipMemsetAsync(flags, 0, 1024, stream);
  pack_w_kern<<<8, 256, 0, stream>>>(Wih0, wp_ih0, 22, 1);
  pack_w_kern<<<32, 256, 0, stream>>>(Whh0, wp_hh0, 128, 4);
  pack_w_kern<<<32, 256, 0, stream>>>(Wih1, wp_ih1, 128, 4);
  pack_w_kern<<<32, 256, 0, stream>>>(Whh1, wp_hh1, 128, 4);
  pack_w_kern<<<32, 256, 0, stream>>>(Wih2, wp_ih2, 128, 4);
  pack_w_kern<<<32, 256, 0, stream>>>(Whh2, wp_hh2, 128, 4);
  pack_emb_kern<<<1024, 256, 0, stream>>>(idx_shops, idx_items,
                                          emb_shops, emb_items, embp);
  lstm_pipe3_kern<<<192, NTHREADS, 0, stream>>>(
      wp_ih0, wp_hh0, wp_ih1, wp_hh1, wp_ih2, wp_hh2,
      x_cont, embp, ring0, ring1, flags,
      b0, b1, b2, Wm, bm, Wa, ba, v, out);
}